// Round 1
// 341.658 us; speedup vs baseline: 1.0093x; 1.0093x over previous
//
#include <hip/hip_runtime.h>
#include <hip/hip_bf16.h>

// Problem dims (fixed by reference)
//   B=128, T=256, D_MODEL=128, D_INNER=256, D_STATE=16, D_CONV=4, DT_RANK=8
// I/O dtype: float32. MFMA bf16 for in_proj/out_proj/x_proj. R12:
//  - scan6: register double-buffered S (B/C) chunk loads. scan5 had VGPR=68 —
//    the 2x ds_read_b128 per t were issued at point-of-use (~120cy exposed LDS
//    latency/step => per-SIMD VALU issue ~17%). Occupancy is grid-capped at
//    2 waves/SIMD (2048 waves total), so VGPR budget up to 256 is FREE:
//    hold chunk c+1's S (128 VGPR) + u/d/z in named [2] buffers (static
//    indexing via hand-written 2-phase loop; runtime-indexed vectors spill).
//  - exp2 with log2e folded into A (saves 4 mul/t); zT load exec-masked q==0.
// Outputs: h (128,128,128) then x_skip (128,256,128), fp32, concatenated.

typedef __attribute__((ext_vector_type(8))) short bf16x8;
typedef __attribute__((ext_vector_type(4))) short bf16x4;
typedef __attribute__((ext_vector_type(4))) float f32x4;
using bf16 = __hip_bfloat16;

static __device__ __forceinline__ short f2s(float v) {
  union { bf16 b; short s; } u; u.b = (bf16)v; return u.s;
}
static __device__ __forceinline__ float s2f(short s) {
  union { short s; bf16 b; } u; u.s = s; return (float)u.b;
}

// ---------------------------------------------------------------------------
// cvt_x: x fp32 -> bf16 xb AND x_skip passthrough (out1), 4 elems/thread.
// ---------------------------------------------------------------------------
__global__ __launch_bounds__(256) void cvt_x(const float* __restrict__ x,
                                             short* __restrict__ xb,
                                             float* __restrict__ out1) {
  int i = (blockIdx.x * 256 + threadIdx.x) * 4;
  f32x4 v = *(const f32x4*)(x + i);
  bf16x4 o;
  o[0] = f2s(v[0]); o[1] = f2s(v[1]); o[2] = f2s(v[2]); o[3] = f2s(v[3]);
  *(bf16x4*)(xb + i) = o;
  *(f32x4*)(out1 + i) = v;
}

// ---------------------------------------------------------------------------
// Weight prep: ipw(512x128)->bf16 (ws), opw(128x256)->bf16 (ws),
// down_w (co,ci,k) -> WT[(k*128+ci)*128+co] fp32 (out0 region),
// x_proj_w -> wxb (64x256 bf16, rows 40..63 zero; out0 region).
// out0 staging is safe: ln_k writes out0 LAST, after all consumers.
// ---------------------------------------------------------------------------
__global__ __launch_bounds__(256) void prep_w(const float* __restrict__ ipw,
                                              const float* __restrict__ opw,
                                              const float* __restrict__ dw,
                                              const float* __restrict__ xpw,
                                              short* __restrict__ ipwb,
                                              short* __restrict__ opwb,
                                              float* __restrict__ wt,
                                              short* __restrict__ wxb) {
  int idx = blockIdx.x * 256 + threadIdx.x;   // 0 .. 163839
  if (idx < 65536) {
    ipwb[idx] = f2s(ipw[idx]);
  } else if (idx < 98304) {
    int j = idx - 65536;
    opwb[j] = f2s(opw[j]);
  } else if (idx < 147456) {
    int j = idx - 98304;          // (k*128+ci)*128 + co
    int co = j & 127;
    int p  = j >> 7;              // k*128+ci
    int k  = p >> 7;
    int ci = p & 127;
    wt[j] = dw[(co * 128 + ci) * 3 + k];
  } else {
    int j = idx - 147456;         // n*256 + k
    int n = j >> 8;
    wxb[j] = (n < 40) ? f2s(xpw[j]) : (short)0;
  }
}

// ---------------------------------------------------------------------------
// MFMA GEMM: C = A(MxK bf16) @ W(NxK bf16)^T. Block 256thr/4 waves, tile
// 64m x 64n, wave = 16 rows x 4 n-frags. mfma_f32_16x16x32_bf16 layouts:
//   A/B frag: row(lane&15), k = (lane>>4)*8 + j
//   C/D frag: col(lane&15), row = (lane>>4)*4 + reg
// MODE 0: fp32 store, ldc=N. MODE 1 (in_proj): col<256 -> bf16 xcpre,
// col>=256 -> bf16 silu -> zact.
// ---------------------------------------------------------------------------
template<int N, int K, int MODE>
__global__ __launch_bounds__(256) void mgemm(const short* __restrict__ A,
                                             const short* __restrict__ W,
                                             float* __restrict__ C,
                                             short* __restrict__ xcpre,
                                             short* __restrict__ zact) {
  const int m_base = blockIdx.x * 64;
  const int n_base = blockIdx.y * 64;
  const int wave = threadIdx.x >> 6;
  const int lane = threadIdx.x & 63;
  const int r16  = lane & 15;
  const int quad = lane >> 4;
  f32x4 acc[4] = {};
  const short* Ap = A + (size_t)(m_base + wave * 16 + r16) * K + quad * 8;
  const short* Wp = W + (size_t)(n_base + r16) * K + quad * 8;
#pragma unroll
  for (int k0 = 0; k0 < K; k0 += 32) {
    bf16x8 a = *(const bf16x8*)(Ap + k0);
#pragma unroll
    for (int j = 0; j < 4; ++j) {
      bf16x8 b = *(const bf16x8*)(Wp + (size_t)j * 16 * K + k0);
      acc[j] = __builtin_amdgcn_mfma_f32_16x16x32_bf16(a, b, acc[j], 0, 0, 0);
    }
  }
#pragma unroll
  for (int j = 0; j < 4; ++j) {
    const int col = n_base + j * 16 + r16;
#pragma unroll
    for (int r = 0; r < 4; ++r) {
      const int row = m_base + wave * 16 + quad * 4 + r;
      if (MODE == 0) {
        C[(size_t)row * N + col] = acc[j][r];
      } else {
        if (col < 256) {
          xcpre[(size_t)row * 256 + col] = f2s(acc[j][r]);
        } else {
          float v = acc[j][r];
          zact[(size_t)row * 256 + (col - 256)] = f2s(v / (1.f + __expf(-v)));
        }
      }
    }
  }
}

// ---------------------------------------------------------------------------
// conv_silu2: depthwise causal conv (width 4) + bias + silu. Block = (b,
// 64-d tile), 256 thr = 64 d-lanes x 4 t-groups of 64. Each thread runs its
// t-range serially (coalesced 128B/wave input reads, 3-tap history in regs).
// Emits xcb (b,t,d) for the x_proj GEMM and, via LDS transpose, xcT (b,d,t)
// with 1KB-coalesced b128 stores.
// ---------------------------------------------------------------------------
__global__ __launch_bounds__(256) void conv_silu2(const short* __restrict__ xcpre,
                                                  const float* __restrict__ cw,
                                                  const float* __restrict__ cb,
                                                  short* __restrict__ xcb,
                                                  short* __restrict__ xcT) {
  const int b  = blockIdx.x >> 2;
  const int dt = (blockIdx.x & 3) * 64;
  const int tg = threadIdx.x >> 6;
  const int dl = threadIdx.x & 63;
  const int d  = dt + dl;
  const int t0 = tg * 64;
  __shared__ short L[64][264];                 // [d][t] bf16, stride 264 (16B-aligned)
  const float w0 = cw[d * 4], w1 = cw[d * 4 + 1], w2 = cw[d * 4 + 2], w3 = cw[d * 4 + 3];
  const float bias = cb[d];
  const size_t base = (size_t)b * 65536 + d;   // xcpre[(b,t,d)] = base + t*256
  float p0 = (t0 >= 3) ? s2f(xcpre[base + (size_t)(t0 - 3) * 256]) : 0.f;
  float p1 = (t0 >= 2) ? s2f(xcpre[base + (size_t)(t0 - 2) * 256]) : 0.f;
  float p2 = (t0 >= 1) ? s2f(xcpre[base + (size_t)(t0 - 1) * 256]) : 0.f;
  for (int t = t0; t < t0 + 64; ++t) {
    float cur = s2f(xcpre[base + (size_t)t * 256]);
    float acc = bias + p0 * w0 + p1 * w1 + p2 * w2 + cur * w3;
    short s = f2s(acc / (1.f + __expf(-acc)));
    xcb[base + (size_t)t * 256] = s;           // coalesced per t
    L[dl][t] = s;
    p0 = p1; p1 = p2; p2 = cur;
  }
  __syncthreads();
  // transpose write-out: per round, wave covers 2 full d-rows -> 1KB contig
#pragma unroll
  for (int r8 = 0; r8 < 8; ++r8) {
    const int dw = r8 * 8 + (threadIdx.x >> 5);
    const int tc = threadIdx.x & 31;
    bf16x8 v = *(const bf16x8*)(&L[dw][tc * 8]);
    *(bf16x8*)(xcT + ((size_t)b * 256 + dt + dw) * 256 + tc * 8) = v;
  }
}

// ---------------------------------------------------------------------------
// repack: delta = softplus(dt . dt_proj_w[d] + b[d]) and z-transpose.
// Same block/tile structure as conv_silu2; emits dT,zT in (b,d,t) bf16.
// ---------------------------------------------------------------------------
__global__ __launch_bounds__(256) void repack(const float* __restrict__ xdbl,
                                              const short* __restrict__ zact,
                                              const float* __restrict__ dtw,
                                              const float* __restrict__ dtb,
                                              short* __restrict__ dT,
                                              short* __restrict__ zT) {
  const int b  = blockIdx.x >> 2;
  const int dt = (blockIdx.x & 3) * 64;
  const int tg = threadIdx.x >> 6;
  const int dl = threadIdx.x & 63;
  const int d  = dt + dl;
  const int t0 = tg * 64;
  __shared__ short Ld[64][264], Lz[64][264];   // 2 x 33,792 B
  float wd[8];
#pragma unroll
  for (int j = 0; j < 8; ++j) wd[j] = dtw[d * 8 + j];
  const float bd = dtb[d];
  for (int t = t0; t < t0 + 64; ++t) {
    const float* r = xdbl + (size_t)(b * 256 + t) * 64;
    float acc = bd;
#pragma unroll
    for (int j = 0; j < 8; ++j) acc += r[j] * wd[j];
    const float delta = (acc > 20.f) ? acc : __logf(1.f + __expf(acc));
    Ld[dl][t] = f2s(delta);
    Lz[dl][t] = zact[(size_t)b * 65536 + (size_t)t * 256 + d];
  }
  __syncthreads();
#pragma unroll
  for (int r8 = 0; r8 < 8; ++r8) {
    const int dw = r8 * 8 + (threadIdx.x >> 5);
    const int tc = threadIdx.x & 31;
    const size_t o = ((size_t)b * 256 + dt + dw) * 256 + tc * 8;
    *(bf16x8*)(dT + o) = *(const bf16x8*)(&Ld[dw][tc * 8]);
    *(bf16x8*)(zT + o) = *(const bf16x8*)(&Lz[dw][tc * 8]);
  }
}

// ---------------------------------------------------------------------------
// scan6: state-parallel selective scan, register-pipelined. Block = (b, group
// of 32 d), 128 thr = 32 d x 4 lanes; lane owns 4 of 16 states, serial T=256.
// Occupancy is grid-capped at 2 waves/SIMD (2048 waves), so VGPR<=256 is free:
// S (B/C fp32, LDS) chunk loads are double-buffered in registers (SBr/SCr
// [2][8] f32x4 = 128 VGPR) with a hand-written 2-phase chunk loop so every
// buffer index is a compile-time constant (runtime-indexed vectors -> scratch).
// u/delta/z stay chunk-double-buffered as before; zT load is exec-masked to
// q==0 (sole consumer). exp2 with log2e pre-folded into A.
// ---------------------------------------------------------------------------
#define SC6_PREFETCH(BUF, CH) do {                                           \
    _Pragma("unroll")                                                        \
    for (int j_ = 0; j_ < 8; ++j_) {                                         \
      SBr[BUF][j_] = *(const f32x4*)(&S[(CH) * 8 + j_][q * 4]);              \
      SCr[BUF][j_] = *(const f32x4*)(&S[(CH) * 8 + j_][16 + q * 4]);         \
    }                                                                        \
    uu[BUF] = *(const bf16x8*)(xcT + tb + (CH) * 8);                         \
    dd[BUF] = *(const bf16x8*)(dT + tb + (CH) * 8);                          \
    if (q == 0) zz[BUF] = *(const bf16x8*)(zT + tb + (CH) * 8);              \
  } while (0)

#define SC6_COMPUTE(BUF, CH) do {                                            \
    _Pragma("unroll")                                                        \
    for (int tt_ = 0; tt_ < 8; ++tt_) {                                      \
      const int t_ = (CH) * 8 + tt_;                                         \
      const float delta_ = s2f(dd[BUF][tt_]);                                \
      const float u_ = s2f(uu[BUF][tt_]);                                    \
      const float du_ = delta_ * u_;                                         \
      const f32x4 Bq_ = SBr[BUF][tt_];                                       \
      const f32x4 Cq_ = SCr[BUF][tt_];                                       \
      float yt_ = 0.f;                                                       \
      _Pragma("unroll")                                                      \
      for (int n_ = 0; n_ < 4; ++n_) {                                       \
        const float dA_ = __builtin_amdgcn_exp2f(delta_ * A2[n_]);           \
        h[n_] = dA_ * h[n_] + du_ * Bq_[n_];                                 \
        yt_ += h[n_] * Cq_[n_];                                              \
      }                                                                      \
      yt_ += __shfl_xor(yt_, 1);                                             \
      yt_ += __shfl_xor(yt_, 2);                                             \
      if (q == 0)                                                            \
        yb[(rb + t_) * 256 + d] = f2s((yt_ + u_ * Dv) * s2f(zz[BUF][tt_]));  \
    }                                                                        \
  } while (0)

__global__ __launch_bounds__(128, 2) void scan6(const float* __restrict__ xdbl,
                                                const short* __restrict__ xcT,
                                                const short* __restrict__ dT,
                                                const short* __restrict__ zT,
                                                const float* __restrict__ alog,
                                                const float* __restrict__ Dp,
                                                short* __restrict__ yb) {
  const int g = blockIdx.x & 7;
  const int b = blockIdx.x >> 3;
  const int q = threadIdx.x & 3;
  const int d = g * 32 + (threadIdx.x >> 2);
  const size_t rb = (size_t)b * 256;
  __shared__ float S[256][32];                // B(16)|C(16) fp32 per t, 32 KB
  for (int i = threadIdx.x; i < 2048; i += 128) {
    int row = i >> 3, c4 = i & 7;
    f32x4 v = *(const f32x4*)(xdbl + (rb + row) * 64 + 8 + c4 * 4);
    *(f32x4*)(&S[row][c4 * 4]) = v;
  }
  float A2[4];
#pragma unroll
  for (int n = 0; n < 4; ++n)
    A2[n] = -__expf(alog[d * 16 + q * 4 + n]) * 1.44269504089f;
  const float Dv = Dp[d];
  float h[4] = {0.f, 0.f, 0.f, 0.f};
  const size_t tb = ((size_t)b * 256 + d) * 256;   // t-row base (b,d,t)
  f32x4 SBr[2][8], SCr[2][8];
  bf16x8 uu[2], dd[2];
  bf16x8 zz[2] = {};
  // global chunk-0 loads can start before the LDS fill is visible
  uu[0] = *(const bf16x8*)(xcT + tb);
  dd[0] = *(const bf16x8*)(dT + tb);
  if (q == 0) zz[0] = *(const bf16x8*)(zT + tb);
  __syncthreads();
#pragma unroll
  for (int j_ = 0; j_ < 8; ++j_) {
    SBr[0][j_] = *(const f32x4*)(&S[j_][q * 4]);
    SCr[0][j_] = *(const f32x4*)(&S[j_][16 + q * 4]);
  }
  for (int c = 0; c < 32; c += 2) {
    SC6_PREFETCH(1, c + 1);
    SC6_COMPUTE(0, c);
    if (c + 2 < 32) SC6_PREFETCH(0, c + 2);
    SC6_COMPUTE(1, c + 1);
  }
}

// ---------------------------------------------------------------------------
// Fused strided down-conv: hd[b,to,co] = sum_{k,ci} h1[b,2to+k-1,ci]*w[co,ci,k]
// + db[co]. Block = (b, 8 'to'), 128 threads; 17 h1 rows in LDS.
// ---------------------------------------------------------------------------
__global__ __launch_bounds__(128) void down_k(const float* __restrict__ h1,
                                              const float* __restrict__ wt,
                                              const float* __restrict__ db,
                                              float* __restrict__ hd) {
  const int b   = blockIdx.x >> 4;
  const int to0 = (blockIdx.x & 15) * 8;
  const int co  = threadIdx.x;
  __shared__ float hs[17][128];
  const int tbase = 2 * to0 - 1;
#pragma unroll
  for (int i = 0; i < 17; ++i) {
    int t = tbase + i;
    hs[i][co] = (t >= 0 && t < 256) ? h1[(size_t)(b * 256 + t) * 128 + co] : 0.f;
  }
  __syncthreads();
  float acc[8];
  const float bias = db[co];
#pragma unroll
  for (int r = 0; r < 8; ++r) acc[r] = bias;
  for (int j = 0; j < 384; ++j) {
    float w = wt[j * 128 + co];
    int k = j >> 7, ci = j & 127;
#pragma unroll
    for (int r = 0; r < 8; ++r) acc[r] += hs[2 * r + k][ci] * w;
  }
#pragma unroll
  for (int r = 0; r < 8; ++r)
    hd[(size_t)(b * 128 + to0 + r) * 128 + co] = acc[r];
}

// ---------------------------------------------------------------------------
// LayerNorm over last dim (128), eps 1e-5. One wave per row, 2 cols/thread.
// ---------------------------------------------------------------------------
__global__ __launch_bounds__(64) void ln_k(const float* __restrict__ hd,
                                           const float* __restrict__ g,
                                           const float* __restrict__ be,
                                           float* __restrict__ out) {
  int row = blockIdx.x;
  const float* r = hd + (size_t)row * 128;
  float v0 = r[threadIdx.x];
  float v1 = r[threadIdx.x + 64];
  float s = v0 + v1;
#pragma unroll
  for (int off = 32; off; off >>= 1) s += __shfl_xor(s, off);
  float mu = s * (1.0f / 128.0f);
  float d0 = v0 - mu, d1 = v1 - mu;
  float vs = d0 * d0 + d1 * d1;
#pragma unroll
  for (int off = 32; off; off >>= 1) vs += __shfl_xor(vs, off);
  float rstd = rsqrtf(vs * (1.0f / 128.0f) + 1e-5f);
  out[(size_t)row * 128 + threadIdx.x]      = d0 * rstd * g[threadIdx.x] + be[threadIdx.x];
  out[(size_t)row * 128 + threadIdx.x + 64] = d1 * rstd * g[threadIdx.x + 64] + be[threadIdx.x + 64];
}

// ---------------------------------------------------------------------------
// Workspace layout (bytes), peak 92,471,296 == proven-safe bound:
//   [0,16M)      xcpre bf16 (in_proj->conv) -> yb bf16 (scan->out_proj)
//                -> hd fp32 8.4MB (down_k->ln)
//   [16M,32M)    xcT bf16 (conv->scan)
//   [32M,48M)    zact bf16 (in_proj->repack)
//   [48M,64M)    xcb bf16 (conv->xproj) -> dT bf16 (repack->scan)
//                -> h1 fp32 (out_proj->down_k)
//   [64M,72M)    xdbl fp32 (xproj->scan)
//   [72M,88M)    xb bf16 8.4MB (cvt->in_proj) -> zT bf16 (repack->scan)
//   [88M,88.2M)  ipwb | opwb bf16  (ends exactly at 92,471,296)
// d_out staging: wt (192KB fp32) + wxb (32KB bf16) in OUT0 region
// (ln_k writes out0 LAST); out1 written once by cvt_x.
// ---------------------------------------------------------------------------
static const size_t O_XCPRE = 0;            // also yb, then hd
static const size_t O_XCT   = 16777216;
static const size_t O_ZACT  = 33554432;
static const size_t O_XCB   = 50331648;     // also dT, then h1
static const size_t O_XDBL  = 67108864;
static const size_t O_XB    = 75497472;     // also zT (16,777,216 B)
static const size_t O_IPWB  = 92274688;     // 131,072 B
static const size_t O_OPWB  = 92405760;     //  65,536 B -> end 92,471,296

extern "C" void kernel_launch(void* const* d_in, const int* in_sizes, int n_in,
                              void* d_out, int out_size, void* d_ws, size_t ws_size,
                              hipStream_t stream) {
  const float* x    = (const float*)d_in[0];
  const float* ipw  = (const float*)d_in[1];
  const float* cw   = (const float*)d_in[2];
  const float* cb   = (const float*)d_in[3];
  const float* xpw  = (const float*)d_in[4];
  const float* dtw  = (const float*)d_in[5];
  const float* dtb  = (const float*)d_in[6];
  const float* alog = (const float*)d_in[7];
  const float* Dp   = (const float*)d_in[8];
  const float* opw  = (const float*)d_in[9];
  const float* dw   = (const float*)d_in[10];
  const float* db   = (const float*)d_in[11];
  const float* lng  = (const float*)d_in[12];
  const float* lnb  = (const float*)d_in[13];

  char*  ws     = (char*)d_ws;
  short* xcpre  = (short*)(ws + O_XCPRE);
  short* yb     = (short*)(ws + O_XCPRE);  // alias (xcpre dead after conv)
  float* hd     = (float*)(ws + O_XCPRE);  // alias (yb dead after out_proj)
  short* xcT    = (short*)(ws + O_XCT);
  short* zact   = (short*)(ws + O_ZACT);
  short* xcb    = (short*)(ws + O_XCB);
  short* dT     = (short*)(ws + O_XCB);    // alias (xcb dead after xproj)
  float* h1     = (float*)(ws + O_XCB);    // alias (dT dead after scan)
  float* xdbl   = (float*)(ws + O_XDBL);
  short* xb     = (short*)(ws + O_XB);
  short* zT     = (short*)(ws + O_XB);     // alias (xb dead after in_proj)
  short* ipwb   = (short*)(ws + O_IPWB);
  short* opwb   = (short*)(ws + O_OPWB);
  float* out    = (float*)d_out;
  float* wt     = out;                     // out0 region; ln_k writes last
  short* wxb    = (short*)(out + 49152);
  float* out1   = out + 2097152;

  // 0. x -> bf16 + x_skip passthrough; weight prep
  cvt_x<<<4096, 256, 0, stream>>>(x, xb, out1);
  prep_w<<<640, 256, 0, stream>>>(ipw, opw, dw, xpw, ipwb, opwb, wt, wxb);
  // 1. in_proj MFMA (32768x512, K=128) -> bf16 xcpre + bf16 silu(z)
  mgemm<512, 128, 1><<<dim3(512, 8), 256, 0, stream>>>(
      xb, ipwb, nullptr, xcpre, zact);
  // 2. depthwise causal conv + silu -> xcb (b,t,d) + xcT (b,d,t)
  conv_silu2<<<512, 256, 0, stream>>>(xcpre, cw, cb, xcb, xcT);
  // 3. x_dbl MFMA: xcb @ wxb^T (32768x64, K=256) -> fp32 xdbl
  mgemm<64, 256, 0><<<dim3(512, 1), 256, 0, stream>>>(
      xcb, wxb, xdbl, nullptr, nullptr);
  // 4. delta + z transpose -> dT, zT (b,d,t)
  repack<<<512, 256, 0, stream>>>(xdbl, zact, dtw, dtb, dT, zT);
  // 5. state-parallel scan (register-pipelined) -> yb bf16
  scan6<<<1024, 128, 0, stream>>>(xdbl, xcT, dT, zT, alog, Dp, yb);
  // 6. out_proj MFMA: h1 = y @ out_proj_w^T (32768x128, K=256), fp32 out
  mgemm<128, 256, 0><<<dim3(512, 2), 256, 0, stream>>>(
      yb, opwb, h1, nullptr, nullptr);
  // 7. fused strided down-conv -> hd (16384x128, ws)
  down_k<<<2048, 128, 0, stream>>>(h1, wt, db, hd);
  // 8. LayerNorm -> output 0 (overwrites wt/wxb staging — consumed already)
  ln_k<<<16384, 64, 0, stream>>>(hd, lng, lnb, out);
}